// Round 1
// baseline (404.237 us; speedup 1.0000x reference)
//
#include <hip/hip_runtime.h>
#include <hip/hip_bf16.h>

#define BATCH 128
#define LQ    512
#define LK    512
#define DH    64
#define TQ    16
#define KC    64     // phase-3 V chunk rows (k per chunk)

// LDS strides (16-bit elements) -- bank-analysis:
//  VROW=72 : Vt rows (36 dwords -> bank=(4d+2p)%32). With swizzle gp=g^(d&15),
//            both transpose-writes and lo/hi b64 reads place exactly 4 lanes on
//            every bank-pair = ds_*_b64 floor (enumerated all 64 lanes).
//  SSTR=520: fp16 scores / bf16 attn overlay; b64 r/w 4-lanes/pair (minimal),
//            b128 phase-3 reads uniform over 8 bank-groups (minimal)
#define VROW  72
#define SSTR  520

typedef float    float4v __attribute__((ext_vector_type(4)));
typedef short    short8v __attribute__((ext_vector_type(8)));
typedef short    short4v __attribute__((ext_vector_type(4)));
typedef int      int4v   __attribute__((ext_vector_type(4)));
typedef _Float16 half4v  __attribute__((ext_vector_type(4)));

__device__ __forceinline__ short bf16r(float f) {
  union { float f; unsigned u; } x; x.f = f;
  unsigned r = x.u + 0x7FFFu + ((x.u >> 16) & 1u);
  return (short)(r >> 16);
}

__global__ __launch_bounds__(256, 6)
void sdpa_kernel(const float* __restrict__ Q, const float* __restrict__ K,
                 const float* __restrict__ V, const int* __restrict__ KM,
                 const int* __restrict__ QM, float* __restrict__ OUT,
                 float* __restrict__ ATT)
{
  __shared__ short kvs[KC * VROW];   // swizzled Vt (phase 3 only; phase 1 is LDS-free)
  __shared__ short scs[TQ * SSTR];   // fp16 scores, then bf16 attn (in place)

  // XCD-contiguous remap: 4096 wgs, 8 XCDs -> each XCD owns 512 consecutive wgs
  // (16 batches; their K+V = 4 MB fits one XCD's private L2). Bijective (4096%8==0).
  const int bid  = blockIdx.x;
  const int wg   = ((bid & 7) << 9) | (bid >> 3);
  const int b    = wg >> 5;
  const int q0   = (wg & 31) * TQ;
  const int tid  = threadIdx.x;
  const int lane = tid & 63;
  const int wave = tid >> 6;
  const int lm   = lane & 15;
  const int quad = lane >> 4;

  // ----- phase-2 row/col mapping, computed early for mask prefetch --------
  const int row = tid >> 4;          // also phase-3 k-block bR
  const int col = tid & 15;          // also phase-3 d-block bC
  const size_t gro = (size_t)(b * LQ + q0 + row) * LK;

  // Prefetch key mask NOW (nontemporal: touched once): ~900-cyc HBM latency
  // overlaps all of phase 1.
  int4v kmv[8];
#pragma unroll
  for (int j = 0; j < 8; ++j)
    kmv[j] = __builtin_nontemporal_load((const int4v*)(KM + gro + col * 4 + j * 64));

  // ---------------- Q A-fragments in registers ---------------------------
  const float* qrow = Q + ((size_t)(b * LQ + q0 + lm)) * DH + quad * 8;
  short8v aq0, aq1;
  {
    float4v f0 = *(const float4v*)(qrow + 0);
    float4v f1 = *(const float4v*)(qrow + 4);
    float4v f2 = *(const float4v*)(qrow + 32);
    float4v f3 = *(const float4v*)(qrow + 36);
#pragma unroll
    for (int e = 0; e < 4; ++e) {
      aq0[e]     = bf16r(f0[e]);
      aq0[e + 4] = bf16r(f1[e]);
      aq1[e]     = bf16r(f2[e]);
      aq1[e + 4] = bf16r(f3[e]);
    }
  }

  // ---------------- Phase 1: S = Q K^T (direct-from-global, no LDS) ------
  // B-fragment = 8 contiguous floats of a K row; K is L2-resident (shared by
  // 32 blocks/batch, XCD-local). Each K row read by exactly one wave.
#pragma unroll
  for (int t = 0; t < 8; ++t) {
    const int T = wave * 8 + t;                 // col tile: n = T*16 + lm
    const float* kr = K + ((size_t)(b * LK + T * 16 + lm)) * DH + quad * 8;
    float4v f0 = *(const float4v*)(kr + 0);
    float4v f1 = *(const float4v*)(kr + 4);
    float4v f2 = *(const float4v*)(kr + 32);
    float4v f3 = *(const float4v*)(kr + 36);
    short8v b0, b1;
#pragma unroll
    for (int e = 0; e < 4; ++e) {
      b0[e]     = bf16r(f0[e]);
      b0[e + 4] = bf16r(f1[e]);
      b1[e]     = bf16r(f2[e]);
      b1[e + 4] = bf16r(f3[e]);
    }
    float4v acc = {0.f, 0.f, 0.f, 0.f};
    acc = __builtin_amdgcn_mfma_f32_16x16x32_bf16(aq0, b0, acc, 0, 0, 0);
    acc = __builtin_amdgcn_mfma_f32_16x16x32_bf16(aq1, b1, acc, 0, 0, 0);
    const int n  = T * 16 + lm;
    const int m0 = quad * 4;
#pragma unroll
    for (int j = 0; j < 4; ++j)
      *(_Float16*)&scs[(m0 + j) * SSTR + n] = (_Float16)acc[j];
  }
  __syncthreads();   // single barrier: scores complete before softmax reads

  // ---------------- Phase 2: masks + softmax -----------------------------
  float s[32];
  float mx = -INFINITY;
#pragma unroll
  for (int j = 0; j < 8; ++j) {
    half4v h4 = *(const half4v*)&scs[row * SSTR + col * 4 + j * 64];
#pragma unroll
    for (int e = 0; e < 4; ++e) {
      float val = kmv[j][e] ? -INFINITY : (float)h4[e];
      s[j * 4 + e] = val;
      mx = fmaxf(mx, val);
    }
  }
  // issue query-mask loads early: latency overlaps shuffles + exp
  int4v qmv[8];
#pragma unroll
  for (int j = 0; j < 8; ++j)
    qmv[j] = __builtin_nontemporal_load((const int4v*)(QM + gro + col * 4 + j * 64));
#pragma unroll
  for (int off = 8; off; off >>= 1) mx = fmaxf(mx, __shfl_xor(mx, off, 64));
  float sum = 0.f;
#pragma unroll
  for (int j = 0; j < 32; ++j) {
    float p = __expf((s[j] - mx) * 0.125f);
    s[j] = p;
    sum += p;
  }
#pragma unroll
  for (int off = 8; off; off >>= 1) sum += __shfl_xor(sum, off, 64);
  const float inv = 1.f / sum;
  float* arow = ATT + gro;
#pragma unroll
  for (int j = 0; j < 8; ++j) {
    int kk = col * 4 + j * 64;
    float4v a4;
#pragma unroll
    for (int e = 0; e < 4; ++e)
      a4[e] = qmv[j][e] ? 0.f : s[j * 4 + e] * inv;
    __builtin_nontemporal_store(a4, (float4v*)(arow + kk));  // fp32 attn, coalesced, touch-once
    short4v ab;
    ab[0] = bf16r(a4[0]); ab[1] = bf16r(a4[1]);
    ab[2] = bf16r(a4[2]); ab[3] = bf16r(a4[3]);
    // in-place overlay: exactly the shorts this thread just read
    *(short4v*)&scs[row * SSTR + kk] = ab;
  }

  // ---------------- Phase 3: O = A V (KC=64 chunks, reg double-buffer) ---
  float4v oacc = {0.f, 0.f, 0.f, 0.f};
  const float* vbase = V + ((size_t)b * LK) * DH;
  // prologue: load chunk 0 (latency hides under overlay stores above)
  float4v va[4];
  {
    const float* vp = vbase + (row * 4) * DH + col * 4;
#pragma unroll
    for (int r = 0; r < 4; ++r) va[r] = *(const float4v*)(vp + r * DH);
  }
#pragma unroll
  for (int kt = 0; kt < 8; ++kt) {
    // register 4x4 transpose + swizzled (g = bR ^ (d&15)) b64 stores
#pragma unroll
    for (int e = 0; e < 4; ++e) {
      int d  = col * 4 + e;
      int gp = row ^ (d & 15);
      short4v s4;
      s4[0] = bf16r(va[0][e]); s4[1] = bf16r(va[1][e]);
      s4[2] = bf16r(va[2][e]); s4[3] = bf16r(va[3][e]);
      *(short4v*)&kvs[d * VROW + gp * 4] = s4;
    }
    // prefetch next chunk into regs; issued before barrier, consumed next iter,
    // so its latency hides under this chunk's MFMA half-phase.
    float4v vb[4];
    if (kt < 7) {
      const float* vp = vbase + ((kt + 1) * KC + row * 4) * DH + col * 4;
#pragma unroll
      for (int r = 0; r < 4; ++r) vb[r] = *(const float4v*)(vp + r * DH);
    }
    __syncthreads();   // also orders phase-2 attn overlay before A-frag reads
#pragma unroll
    for (int ks = 0; ks < 2; ++ks) {
      const short* ap = &scs[lm * SSTR + kt * KC + ks * 32 + quad * 8];
      short8v a8 = *(const short8v*)ap;
      int n  = wave * 16 + lm;
      int g0 = ks * 8 + quad * 2;
      short4v lo = *(const short4v*)&kvs[n * VROW + ((g0    ) ^ (n & 15)) * 4];
      short4v hi = *(const short4v*)&kvs[n * VROW + ((g0 + 1) ^ (n & 15)) * 4];
      short8v b8;
      b8[0] = lo[0]; b8[1] = lo[1]; b8[2] = lo[2]; b8[3] = lo[3];
      b8[4] = hi[0]; b8[5] = hi[1]; b8[6] = hi[2]; b8[7] = hi[3];
      oacc = __builtin_amdgcn_mfma_f32_16x16x32_bf16(a8, b8, oacc, 0, 0, 0);
    }
    __syncthreads();
#pragma unroll
    for (int r = 0; r < 4; ++r) va[r] = vb[r];
  }
  {
    int m0 = quad * 4;
    float* obase = OUT + ((size_t)(b * LQ + q0 + m0)) * DH + wave * 16 + lm;
    obase[0 * DH] = oacc[0];
    obase[1 * DH] = oacc[1];
    obase[2 * DH] = oacc[2];
    obase[3 * DH] = oacc[3];
  }
}

extern "C" void kernel_launch(void* const* d_in, const int* in_sizes, int n_in,
                              void* d_out, int out_size, void* d_ws, size_t ws_size,
                              hipStream_t stream) {
  const float* q  = (const float*)d_in[0];
  const float* k  = (const float*)d_in[1];
  const float* v  = (const float*)d_in[2];
  const int*   km = (const int*)d_in[3];
  const int*   qm = (const int*)d_in[4];
  float* out  = (float*)d_out;
  float* attn = out + (size_t)BATCH * LQ * DH;
  dim3 grid(BATCH * (LQ / TQ));
  dim3 block(256);
  hipLaunchKernelGGL(sdpa_kernel, grid, block, 0, stream,
                     q, k, v, km, qm, out, attn);
}